// Round 10
// baseline (2655.018 us; speedup 1.0000x reference)
//
#include <hip/hip_runtime.h>
#include <hip/hip_bf16.h>
#include <stdint.h>

typedef __attribute__((ext_vector_type(4))) float    f32x4;
typedef __attribute__((ext_vector_type(8))) short    bf16x8;
typedef __attribute__((ext_vector_type(2))) uint32_t u32x2;
typedef __attribute__((ext_vector_type(4))) uint32_t u32x4;
typedef unsigned short u16;

#define T_   256
#define B_   64
#define E_   1024
#define H_   1024
#define CLS  32000
#define NWG  256

// workspace layout (bytes)
#define OFF_XBF   0ull            // [T*B][E] bf16            33,554,432  (dead after GEMM)
#define OFF_CNT   OFF_XBF         // [2][4 pair][128 wg][2] u32 subflags 8,192 (alias)
#define OFF_WIALL 33554432ull     // [8192][1024] bf16        16,777,216
#define OFF_XP    50331648ull     // [16384][256 wg][32] bf16 268,435,456 (per-wg packed)
#define OFF_WHP   318767104ull    // [256 wg][32768 u16]      16,777,216
#define OFF_BSUM  335544320ull    // [2][4096] f32                32,768
#define OFF_OBUF  336101376ull    // [2 dir][64][1024] f32       524,288
#define OFF_OSUM  336625664ull    // [64][1024] bf16             131,072
#define OFF_HROT  336756736ull    // [257][2][128 wg][64][8] bf16 67,371,008 (rotating h)
#define HROT_END  404127744ull

__device__ __forceinline__ u16 f2bf(float f) {
    union { float f; uint32_t i; } v; v.f = f;
    uint32_t r = v.i + 0x7fffu + ((v.i >> 16) & 1u);
    return (u16)(r >> 16);
}
__device__ __forceinline__ float bf2f(u16 u) {
    union { uint32_t i; float f; } v; v.i = ((uint32_t)u) << 16; return v.f;
}
__device__ __forceinline__ float sigm(float x)   { return 1.f / (1.f + __expf(-x)); }
__device__ __forceinline__ float tanh_f(float x) { return 1.f - 2.f / (__expf(2.f * x) + 1.f); }

// agent-coherent (MALL) accesses — bypass L1/L2, no cache-wide ops anywhere
__device__ __forceinline__ void ldg8_cc(u32x2& d, const unsigned* p) {
    asm volatile("global_load_dwordx2 %0, %1, off sc0 sc1"
                 : "=v"(d) : "v"(p) : "memory");
}
__device__ __forceinline__ void stg16_cc(u16* p, bf16x8 v) {
    asm volatile("global_store_dwordx4 %0, %1, off sc0 sc1"
                 :: "v"(p), "v"(v) : "memory");
}
__device__ __forceinline__ void stg4_cc(unsigned* p, unsigned v) {
    asm volatile("global_store_dword %0, %1, off sc0 sc1"
                 :: "v"(p), "v"(v) : "memory");
}
__device__ __forceinline__ void wait_vm0() {
    asm volatile("s_waitcnt vmcnt(0)" ::: "memory");
}

// ---------------- prep kernels ----------------

__global__ void k_gather(const int* __restrict__ X, const float* __restrict__ emb,
                         u16* __restrict__ xbf) {
    const int m = blockIdx.x;            // t*64+b
    const int t = m >> 6, b = m & 63;
    const int tok = X[b * T_ + t];
    const float* src = emb + (size_t)tok * E_;
    u16* dst = xbf + (size_t)m * E_;
    const int e = threadIdx.x * 4;
    float4 v = *(const float4*)(src + e);
    ushort4 o; o.x = f2bf(v.x); o.y = f2bf(v.y); o.z = f2bf(v.z); o.w = f2bf(v.w);
    *(ushort4*)(dst + e) = o;
}

__global__ void k_cvt(const float* __restrict__ src, u16* __restrict__ dst) {
    const int i = (blockIdx.x * 256 + threadIdx.x) * 4;
    float4 v = *(const float4*)(src + i);
    ushort4 o; o.x = f2bf(v.x); o.y = f2bf(v.y); o.z = f2bf(v.z); o.w = f2bf(v.w);
    *(ushort4*)(dst + i) = o;
}

// pack Wh per logical wg (dir*128+hblk), B-fragment order, XOR-swizzled 16B groups
__global__ void k_packwh(const float* __restrict__ Wh1, const float* __restrict__ Wh2,
                         u16* __restrict__ whp) {
    const int gi  = blockIdx.x * 256 + threadIdx.x;
    const int wg  = gi >> 12;
    const int lin = gi & 4095;
    const int kc  = lin & 127;
    const int col = lin >> 7;                          // 0..31
    const int dir = wg >> 7, hblk = wg & 127;
    const int g = col >> 3, hh = col & 7;
    const float* src = (dir ? Wh2 : Wh1) + (size_t)(g * H_ + hblk * 8 + hh) * H_ + kc * 8;
    float4 v0 = *(const float4*)(src);
    float4 v1 = *(const float4*)(src + 4);
    const uint32_t boff = (uint32_t)(((kc * 32 + col) * 16) ^ ((kc & 3) << 4));
    u16* dst = whp + (size_t)wg * 32768 + boff / 2;
    ushort4 o0, o1;
    o0.x = f2bf(v0.x); o0.y = f2bf(v0.y); o0.z = f2bf(v0.z); o0.w = f2bf(v0.w);
    o1.x = f2bf(v1.x); o1.y = f2bf(v1.y); o1.z = f2bf(v1.z); o1.w = f2bf(v1.w);
    *(ushort4*)dst = o0;
    *(ushort4*)(dst + 4) = o1;
}

__global__ void k_bias(const float* __restrict__ bi1, const float* __restrict__ bh1,
                       const float* __restrict__ bi2, const float* __restrict__ bh2,
                       float* __restrict__ bsum) {
    const int i = blockIdx.x * 256 + threadIdx.x;     // 0..8191
    bsum[i] = (i < 4096) ? (bi1[i] + bh1[i]) : (bi2[i - 4096] + bh2[i - 4096]);
}

// ---------------- xp GEMM (epilogue stores per-logical-wg packed layout) ----------------

#define GLDS16(gp, lp) __builtin_amdgcn_global_load_lds( \
    (const __attribute__((address_space(1))) uint32_t*)(gp), \
    (__attribute__((address_space(3))) uint32_t*)(lp), 16, 0, 0)

__global__ __launch_bounds__(256) void k_gemm_xp(const u16* __restrict__ A,
                                                 const u16* __restrict__ Bw,
                                                 u16* __restrict__ Cp) {
    __shared__ __align__(16) u16 As[128 * 32];
    __shared__ __align__(16) u16 Bs[128 * 32];
    const int bid = blockIdx.x;
    const int bn = bid & 63, bm = bid >> 6;
    const int tid = threadIdx.x;
    const int wid = tid >> 6, lane = tid & 63;
    const int wm = wid & 1, wn = wid >> 1;
    const int col16 = lane & 15, kslot = lane >> 4;
    const char* Abase = (const char*)A + (size_t)bm * 128 * 2048;
    const char* Bbase = (const char*)Bw + (size_t)bn * 128 * 2048;
    const int rowoff = (lane >> 2) * 2048 + (lane & 3) * 16;
    f32x4 acc[4][4] = {};
    for (int kt = 0; kt < 32; ++kt) {
        const int ko = kt * 64;
#pragma unroll
        for (int q = 0; q < 2; ++q) {
            const int ci = q * 4 + wid;
            GLDS16(Abase + (size_t)ci * 16 * 2048 + rowoff + ko, (char*)As + ci * 1024);
            GLDS16(Bbase + (size_t)ci * 16 * 2048 + rowoff + ko, (char*)Bs + ci * 1024);
        }
        __syncthreads();
        bf16x8 af[4], bfr[4];
#pragma unroll
        for (int mi = 0; mi < 4; ++mi)
            af[mi] = *(const bf16x8*)(As + (wm * 64 + mi * 16 + col16) * 32 + kslot * 8);
#pragma unroll
        for (int ni = 0; ni < 4; ++ni)
            bfr[ni] = *(const bf16x8*)(Bs + (wn * 64 + ni * 16 + col16) * 32 + kslot * 8);
#pragma unroll
        for (int mi = 0; mi < 4; ++mi)
#pragma unroll
            for (int ni = 0; ni < 4; ++ni)
                acc[mi][ni] = __builtin_amdgcn_mfma_f32_16x16x32_bf16(af[mi], bfr[ni], acc[mi][ni], 0, 0, 0);
        __syncthreads();
    }
    // store xp packed per consumer logical wg: xp[row][lwg][fh*4+g]
#pragma unroll
    for (int mi = 0; mi < 4; ++mi)
#pragma unroll
        for (int ni = 0; ni < 4; ++ni)
#pragma unroll
            for (int q = 0; q < 4; ++q) {
                const int r  = bm * 128 + wm * 64 + mi * 16 + kslot * 4 + q;
                const int cn = bn * 128 + wn * 64 + ni * 16 + col16;
                const int dircol = cn >> 12, c = cn & 4095;
                const int g = c >> 10, hidx = c & 1023;
                const int wgc = dircol * 128 + (hidx >> 3), fhc = hidx & 7;
                Cp[((size_t)r * 256 + wgc) * 32 + fhc * 4 + g] = f2bf(acc[mi][ni][q]);
            }
}

// ---------------- persistent recurrent kernel ----------------
// 256 wgs x 512 thr, 1 wg/CU. XCD-partitioned: dir = (blockIdx&7)>>2.
// Waves: (mtile 0..3, khalf 0..1). Per step, ONE intra-wg barrier.
// Publish: wave-local LDS transpose -> lanes<8 emit the wave's 128 B as one
// global_store_dwordx4 (sc0 sc1) -> per-wave ack -> per-wave subflag.
// Flags [dir][pair][hblk][2]: consumer wave (mtile,khalf) polls exactly the 2
// producer-wave subflags (mtile*2, mtile*2+1) it depends on, one dwordx2/lane.
// Same-wg glds reuse guarded by lds_done (readers passed finish phase).
// h transport: rotating buffer (stride fixed: 65536 u16 per (step,dir)) ->
// normal cached loads (XCD L2 broadcast), zero cache maintenance.
__global__ __launch_bounds__(512, 1) void k_lstm(
    const u16* __restrict__ xp, const u16* __restrict__ whp,
    const float* __restrict__ bsum, u16* hrot,
    float* __restrict__ obuf, unsigned* cnt) {
    __shared__ __align__(16) u16 wlds[32768];    // 64 KB Wh slice
    __shared__ float glds[2][64][35];            // [khalf][row][col] partial gates
    __shared__ __align__(16) u16 hxch[8][64];    // per-wave h transpose buffer
    __shared__ int lds_done[8];                  // per-wave finish-step marker
    const int pwg = blockIdx.x;
    const int xcd = pwg & 7;
    const int dir = xcd >> 2;                    // XCDs 0-3 -> dir0, 4-7 -> dir1
    const int hblk = (pwg >> 3) * 4 + (xcd & 3); // 0..127
    const int lwg = dir * 128 + hblk;            // logical wg index
    const int tid = threadIdx.x;
    const int wid = tid >> 6, lane = tid & 63;
    const int mtile = wid & 3, khalf = wid >> 2;
    const int col16 = lane & 15, kslot = lane >> 4;
    {   // preload Wh slice (swizzle baked in by k_packwh)
        const u32x4* s = (const u32x4*)(whp + (size_t)lwg * 32768);
        u32x4* d = (u32x4*)wlds;
#pragma unroll
        for (int i = 0; i < 8; ++i) d[tid + i * 512] = s[tid + i * 512];
    }
    const int fb = tid >> 3, fh = tid & 7;       // finish-phase (batch, h-sub)
    const int hidx = hblk * 8 + fh;
    const int arow = mtile * 16 + col16;         // batch row for A-frags
    float bsF[4];
#pragma unroll
    for (int g = 0; g < 4; ++g) bsF[g] = bsum[dir * 4096 + g * 1024 + hidx];
    // consumer poll: pair=mtile, producer hblk=khalf*64+lane, 2 dwords
    const unsigned* pollp = cnt + (size_t)(((dir * 4 + mtile) * 128) + khalf * 64 + lane) * 2;
    // producer subflag: pair=wid>>1, entry=wid&1
    unsigned* flag_own = cnt + (size_t)((dir * 4 + (wid >> 1)) * 128 + hblk) * 2 + (wid & 1);
    if (tid < 8) lds_done[tid] = 0;
    float cc = 0.f;
    ushort4 xv;
    xv = *(const ushort4*)(xp + ((size_t)((dir ? (T_ - 1) : 0) * 64 + fb) * 256 + lwg) * 32 + fh * 4);
    __syncthreads();                              // wlds + lds_done ready
    for (int s = 0; s < T_; ++s) {
        if (s > 0) {
            const unsigned t = (unsigned)s;
            for (;;) {                            // every wave: its 2 subflags x 64 producers
                u32x2 f;
                ldg8_cc(f, pollp);
                wait_vm0();
                if (__all(f[0] >= t && f[1] >= t)) break;
                __builtin_amdgcn_s_sleep(1);
            }
            // own-wg guard: readers of our glds rows passed their finish phase
            volatile int* ld = lds_done;
            while (ld[mtile * 2] < s || ld[mtile * 2 + 1] < s)
                __builtin_amdgcn_s_sleep(1);
        }
        __builtin_amdgcn_sched_barrier(0);        // pin h loads behind the poll
        // ---- h @ Wh^T : cached 16B A-frag loads from contiguous per-wg slices
        const u16* hbase = hrot + (size_t)(s * 2 + dir) * 65536;
        bf16x8 hf[16];
#pragma unroll
        for (int kk = 0; kk < 16; ++kk) {
            const int kc = khalf * 64 + kk * 4 + kslot;
            hf[kk] = *(const bf16x8*)(hbase + (size_t)kc * 512 + arow * 8);
        }
        f32x4 acc0 = {0.f, 0.f, 0.f, 0.f}, acc1 = {0.f, 0.f, 0.f, 0.f};
#pragma unroll
        for (int kk = 0; kk < 16; ++kk) {
            const int kc = khalf * 64 + kk * 4 + kslot;
            const uint32_t base = (uint32_t)(kc * 512);
            const uint32_t sw = (uint32_t)((kc & 3) << 4);
            bf16x8 b0 = *(const bf16x8*)((const char*)wlds + ((base + (uint32_t)(col16 * 16)) ^ sw));
            bf16x8 b1 = *(const bf16x8*)((const char*)wlds + ((base + (uint32_t)(256 + col16 * 16)) ^ sw));
            acc0 = __builtin_amdgcn_mfma_f32_16x16x32_bf16(hf[kk], b0, acc0, 0, 0, 0);
            acc1 = __builtin_amdgcn_mfma_f32_16x16x32_bf16(hf[kk], b1, acc1, 0, 0, 0);
        }
#pragma unroll
        for (int q = 0; q < 4; ++q) {
            glds[khalf][mtile * 16 + kslot * 4 + q][col16]      = acc0[q];
            glds[khalf][mtile * 16 + kslot * 4 + q][16 + col16] = acc1[q];
        }
        __syncthreads();                          // barrier A: gates ready
        // ---- finish: gates -> elementwise -> wave-local transpose publish ----
        const float gi = glds[0][fb][fh]      + glds[1][fb][fh]      + bsF[0] + bf2f(xv.x);
        const float gf = glds[0][fb][8 + fh]  + glds[1][fb][8 + fh]  + bsF[1] + bf2f(xv.y);
        const float gc = glds[0][fb][16 + fh] + glds[1][fb][16 + fh] + bsF[2] + bf2f(xv.z);
        const float go = glds[0][fb][24 + fh] + glds[1][fb][24 + fh] + bsF[3] + bf2f(xv.w);
        const float iv = sigm(gi), fv = sigm(gf), gv = tanh_f(gc), ov = sigm(go);
        cc = fv * cc + iv * gv;
        const float hv = ov * tanh_f(cc);
        hxch[wid][lane] = f2bf(hv);               // wave-private row; no barrier
        if (s == T_ - 1) obuf[(size_t)(dir * 64 + fb) * 1024 + hidx] = ov;
        asm volatile("s_waitcnt lgkmcnt(0)" ::: "memory");
        __builtin_amdgcn_sched_barrier(0);
        if (lane < 8) {                           // 8 lanes x 16B = wave's 128B slice
            bf16x8 hv8 = *(const bf16x8*)(&hxch[wid][lane * 8]);
            u16* hst = hrot + (size_t)((s + 1) * 2 + dir) * 65536
                     + hblk * 512 + wid * 64 + lane * 8;
            stg16_cc(hst, hv8);
        }
        asm volatile("s_waitcnt lgkmcnt(0)" ::: "memory");
        wait_vm0();                               // this wave's slice at MALL
        if (lane == 0) {
            stg4_cc(flag_own, (unsigned)(s + 1));
            lds_done[wid] = s + 1;                // release same-wg glds writers
        }
        if (s < T_ - 1) {                         // xp prefetch AFTER flag (off ack path)
            const int tn = dir ? (T_ - 2 - s) : (s + 1);
            xv = *(const ushort4*)(xp + ((size_t)(tn * 64 + fb) * 256 + lwg) * 32 + fh * 4);
        }
    }
}

// ---------------- epilogue ----------------

__global__ void k_osum(const float* __restrict__ obuf, u16* __restrict__ osum) {
    const int i = blockIdx.x * 256 + threadIdx.x;   // 65536
    osum[i] = f2bf(obuf[i] + obuf[65536 + i]);
}

__global__ __launch_bounds__(256) void k_cls(const u16* __restrict__ osum,
                                             const float* __restrict__ W,
                                             const float* __restrict__ bias,
                                             float* __restrict__ out) {
    const int blk = blockIdx.x;                     // 0..249
    const int tid = threadIdx.x, wid = tid >> 6, lane = tid & 63;
    const int col16 = lane & 15, kslot = lane >> 4;
    const int ncol0 = blk * 128 + wid * 32;
    f32x4 acc[4][2] = {};
    for (int kk = 0; kk < 32; ++kk) {
        const int kof = kk * 32 + kslot * 8;
        bf16x8 a[4];
#pragma unroll
        for (int mi = 0; mi < 4; ++mi)
            a[mi] = *(const bf16x8*)(osum + (mi * 16 + col16) * 1024 + kof);
#pragma unroll
        for (int nt = 0; nt < 2; ++nt) {
            const float* wr = W + (size_t)(ncol0 + nt * 16 + col16) * 1024 + kof;
            float4 w0 = *(const float4*)wr;
            float4 w1 = *(const float4*)(wr + 4);
            union { bf16x8 v; u16 u[8]; } bb;
            bb.u[0] = f2bf(w0.x); bb.u[1] = f2bf(w0.y); bb.u[2] = f2bf(w0.z); bb.u[3] = f2bf(w0.w);
            bb.u[4] = f2bf(w1.x); bb.u[5] = f2bf(w1.y); bb.u[6] = f2bf(w1.z); bb.u[7] = f2bf(w1.w);
#pragma unroll
            for (int mi = 0; mi < 4; ++mi)
                acc[mi][nt] = __builtin_amdgcn_mfma_f32_16x16x32_bf16(a[mi], bb.v, acc[mi][nt], 0, 0, 0);
        }
    }
#pragma unroll
    for (int nt = 0; nt < 2; ++nt) {
        const int cn = ncol0 + nt * 16 + col16;
        const float bv = bias[cn];
#pragma unroll
        for (int mi = 0; mi < 4; ++mi)
#pragma unroll
            for (int q = 0; q < 4; ++q)
                out[(size_t)(mi * 16 + kslot * 4 + q) * CLS + cn] = acc[mi][nt][q] + bv;
    }
}

// ---------------- launcher ----------------

extern "C" void kernel_launch(void* const* d_in, const int* in_sizes, int n_in,
                              void* d_out, int out_size, void* d_ws, size_t ws_size,
                              hipStream_t stream) {
    const int*   X   = (const int*)d_in[0];
    const float* emb = (const float*)d_in[1];
    const float* Wi1 = (const float*)d_in[2];
    const float* Wh1 = (const float*)d_in[3];
    const float* bi1 = (const float*)d_in[4];
    const float* bh1 = (const float*)d_in[5];
    const float* Wi2 = (const float*)d_in[6];
    const float* Wh2 = (const float*)d_in[7];
    const float* bi2 = (const float*)d_in[8];
    const float* bh2 = (const float*)d_in[9];
    const float* W   = (const float*)d_in[10];
    const float* bb  = (const float*)d_in[11];
    float* out = (float*)d_out;
    char* ws = (char*)d_ws;

    u16*      xbf   = (u16*)(ws + OFF_XBF);
    u16*      wiall = (u16*)(ws + OFF_WIALL);
    u16*      xpb   = (u16*)(ws + OFF_XP);
    u16*      whp   = (u16*)(ws + OFF_WHP);
    float*    bsum  = (float*)(ws + OFF_BSUM);
    float*    obuf  = (float*)(ws + OFF_OBUF);
    u16*      osum  = (u16*)(ws + OFF_OSUM);
    u16*      hrot  = (u16*)(ws + OFF_HROT);
    unsigned* cnt   = (unsigned*)(ws + OFF_CNT);   // aliases xbf (dead after GEMM)

    k_gather<<<dim3(16384), dim3(256), 0, stream>>>(X, emb, xbf);
    k_cvt<<<dim3(4096), dim3(256), 0, stream>>>(Wi1, wiall);
    k_cvt<<<dim3(4096), dim3(256), 0, stream>>>(Wi2, wiall + 4194304);
    k_packwh<<<dim3(4096), dim3(256), 0, stream>>>(Wh1, Wh2, whp);
    k_bias<<<dim3(32), dim3(256), 0, stream>>>(bi1, bh1, bi2, bh2, bsum);
    hipMemsetAsync(hrot, 0, 262144, stream);       // h_0 = 0: slots (0,dir0)+(0,dir1)
    k_gemm_xp<<<dim3(8192), dim3(256), 0, stream>>>(xbf, wiall, xpb);
    hipMemsetAsync(cnt, 0, 8192, stream);          // xbf dead; subflags live there
    {
        const u16* xp_p = xpb; const u16* whp_p = whp; const float* bs_p = bsum;
        u16* hr_p = hrot; float* ob_p = obuf; unsigned* cnt_p = cnt;
        void* args[] = { (void*)&xp_p, (void*)&whp_p, (void*)&bs_p,
                         (void*)&hr_p, (void*)&ob_p, (void*)&cnt_p };
        hipError_t e = hipLaunchCooperativeKernel((void*)k_lstm, dim3(NWG), dim3(512),
                                                  args, 0, stream);
        if (e != hipSuccess) {
            // fallback: 256 wgs at 1 wg/CU are co-resident on a 256-CU chip
            k_lstm<<<dim3(NWG), dim3(512), 0, stream>>>(xpb, whp, bsum, hrot, obuf, cnt);
        }
    }
    k_osum<<<dim3(256), dim3(256), 0, stream>>>(obuf, osum);
    k_cls<<<dim3(250), dim3(256), 0, stream>>>(osum, W, bb, out);
    (void)in_sizes; (void)n_in; (void)out_size; (void)ws_size;
}

// Round 11
// 1762.003 us; speedup vs baseline: 1.5068x; 1.5068x over previous
//
#include <hip/hip_runtime.h>
#include <hip/hip_bf16.h>
#include <stdint.h>

typedef __attribute__((ext_vector_type(4))) float    f32x4;
typedef __attribute__((ext_vector_type(8))) short    bf16x8;
typedef __attribute__((ext_vector_type(4))) uint32_t u32x4;
typedef unsigned short u16;

#define T_   256
#define B_   64
#define E_   1024
#define H_   1024
#define CLS  32000
#define NWG  256

// workspace layout (bytes)
#define OFF_XBF   0ull            // [T*B][E] bf16            33,554,432  (dead after GEMM)
#define OFF_CNT   OFF_XBF         // [2*128] flags, 128B apart     32,768 (alias, memset post-GEMM)
#define OFF_WIALL 33554432ull     // [8192][1024] bf16        16,777,216
#define OFF_XP    50331648ull     // [16384][256 wg][32] bf16 268,435,456 (per-wg packed)
#define OFF_WHP   318767104ull    // [256 wg][32768 u16]      16,777,216
#define OFF_BSUM  335544320ull    // [2][4096] f32                32,768
#define OFF_OBUF  336101376ull    // [2 dir][64][1024] f32       524,288
#define OFF_OSUM  336625664ull    // [64][1024] bf16             131,072
#define OFF_HROT  336756736ull    // rotating h: slot (s,dir) at (s*2+dir)*262144 B

__device__ __forceinline__ u16 f2bf(float f) {
    union { float f; uint32_t i; } v; v.f = f;
    uint32_t r = v.i + 0x7fffu + ((v.i >> 16) & 1u);
    return (u16)(r >> 16);
}
__device__ __forceinline__ float bf2f(u16 u) {
    union { uint32_t i; float f; } v; v.i = ((uint32_t)u) << 16; return v.f;
}
__device__ __forceinline__ float sigm(float x)   { return 1.f / (1.f + __expf(-x)); }
__device__ __forceinline__ float tanh_f(float x) { return 1.f - 2.f / (__expf(2.f * x) + 1.f); }

// agent-coherent (MALL) accesses — bypass L1/L2, no cache-wide ops anywhere
__device__ __forceinline__ void ldg4_cc(unsigned& d, const unsigned* p) {
    asm volatile("global_load_dword %0, %1, off sc0 sc1"
                 : "=v"(d) : "v"(p) : "memory");
}
__device__ __forceinline__ void stg16_cc(u16* p, bf16x8 v) {
    asm volatile("global_store_dwordx4 %0, %1, off sc0 sc1"
                 :: "v"(p), "v"(v) : "memory");
}
__device__ __forceinline__ void stg4_cc(unsigned* p, unsigned v) {
    asm volatile("global_store_dword %0, %1, off sc0 sc1"
                 :: "v"(p), "v"(v) : "memory");
}
__device__ __forceinline__ void wait_vm0() {
    asm volatile("s_waitcnt vmcnt(0)" ::: "memory");
}

// ---------------- prep kernels ----------------

__global__ void k_gather(const int* __restrict__ X, const float* __restrict__ emb,
                         u16* __restrict__ xbf) {
    const int m = blockIdx.x;            // t*64+b
    const int t = m >> 6, b = m & 63;
    const int tok = X[b * T_ + t];
    const float* src = emb + (size_t)tok * E_;
    u16* dst = xbf + (size_t)m * E_;
    const int e = threadIdx.x * 4;
    float4 v = *(const float4*)(src + e);
    ushort4 o; o.x = f2bf(v.x); o.y = f2bf(v.y); o.z = f2bf(v.z); o.w = f2bf(v.w);
    *(ushort4*)(dst + e) = o;
}

__global__ void k_cvt(const float* __restrict__ src, u16* __restrict__ dst) {
    const int i = (blockIdx.x * 256 + threadIdx.x) * 4;
    float4 v = *(const float4*)(src + i);
    ushort4 o; o.x = f2bf(v.x); o.y = f2bf(v.y); o.z = f2bf(v.z); o.w = f2bf(v.w);
    *(ushort4*)(dst + i) = o;
}

// pack Wh per logical wg (dir*128+hblk), B-fragment order, XOR-swizzled 16B groups
__global__ void k_packwh(const float* __restrict__ Wh1, const float* __restrict__ Wh2,
                         u16* __restrict__ whp) {
    const int gi  = blockIdx.x * 256 + threadIdx.x;
    const int wg  = gi >> 12;
    const int lin = gi & 4095;
    const int kc  = lin & 127;
    const int col = lin >> 7;                          // 0..31
    const int dir = wg >> 7, hblk = wg & 127;
    const int g = col >> 3, hh = col & 7;
    const float* src = (dir ? Wh2 : Wh1) + (size_t)(g * H_ + hblk * 8 + hh) * H_ + kc * 8;
    float4 v0 = *(const float4*)(src);
    float4 v1 = *(const float4*)(src + 4);
    const uint32_t boff = (uint32_t)(((kc * 32 + col) * 16) ^ ((kc & 3) << 4));
    u16* dst = whp + (size_t)wg * 32768 + boff / 2;
    ushort4 o0, o1;
    o0.x = f2bf(v0.x); o0.y = f2bf(v0.y); o0.z = f2bf(v0.z); o0.w = f2bf(v0.w);
    o1.x = f2bf(v1.x); o1.y = f2bf(v1.y); o1.z = f2bf(v1.z); o1.w = f2bf(v1.w);
    *(ushort4*)dst = o0;
    *(ushort4*)(dst + 4) = o1;
}

__global__ void k_bias(const float* __restrict__ bi1, const float* __restrict__ bh1,
                       const float* __restrict__ bi2, const float* __restrict__ bh2,
                       float* __restrict__ bsum) {
    const int i = blockIdx.x * 256 + threadIdx.x;     // 0..8191
    bsum[i] = (i < 4096) ? (bi1[i] + bh1[i]) : (bi2[i - 4096] + bh2[i - 4096]);
}

// ---------------- xp GEMM ----------------
// Block bn covers a GATHERED column set: 4 hblks x 8 fh x 4 g (dircol = bn>>5,
// hblk0 = (bn&31)*4), local col j -> cn(j) = dircol*4096 + (j&3)*1024 +
// (hblk0 + (j>>5))*8 + ((j>>2)&7). With this mapping the packed-xp output of
// one block is CONTIGUOUS per row (offset = row*8192 + nbase + j), so the
// epilogue stages C in LDS and emits 16B coalesced stores (vs 64 scattered
// 2B stores/thread before). B-tile rows are gathered per-lane (global_load_lds
// source is per-lane -> free). Consumer layout is bit-identical.

#define GLDS16(gp, lp) __builtin_amdgcn_global_load_lds( \
    (const __attribute__((address_space(1))) uint32_t*)(gp), \
    (__attribute__((address_space(3))) uint32_t*)(lp), 16, 0, 0)

__global__ __launch_bounds__(256) void k_gemm_xp(const u16* __restrict__ A,
                                                 const u16* __restrict__ Bw,
                                                 u16* __restrict__ Cp) {
    __shared__ __align__(16) u16 smem[16384];   // As[4096] | Bs[4096] ; reused as C-stage
    u16* As = smem;
    u16* Bs = smem + 4096;
    const int bid = blockIdx.x;
    const int bn = bid & 63, bm = bid >> 6;
    const int tid = threadIdx.x;
    const int wid = tid >> 6, lane = tid & 63;
    const int wm = wid & 1, wn = wid >> 1;
    const int col16 = lane & 15, kslot = lane >> 4;
    const int dircol = bn >> 5, hblk0 = (bn & 31) * 4;
    const char* Abase = (const char*)A + (size_t)bm * 128 * 2048;
    const int rowoff = (lane >> 2) * 2048 + (lane & 3) * 16;
    f32x4 acc[4][4] = {};
    for (int kt = 0; kt < 32; ++kt) {
        const int ko = kt * 64;
#pragma unroll
        for (int q = 0; q < 2; ++q) {
            const int ci = q * 4 + wid;
            GLDS16(Abase + (size_t)ci * 16 * 2048 + rowoff + ko, (char*)As + ci * 1024);
            const int jr  = ci * 16 + (lane >> 2);     // local col (B row) this lane stages
            const int cnr = dircol * 4096 + (jr & 3) * 1024
                          + (hblk0 + (jr >> 5)) * 8 + ((jr >> 2) & 7);
            GLDS16((const char*)Bw + (size_t)cnr * 2048 + (lane & 3) * 16 + ko,
                   (char*)Bs + ci * 1024);
        }
        __syncthreads();
        bf16x8 af[4], bfr[4];
#pragma unroll
        for (int mi = 0; mi < 4; ++mi)
            af[mi] = *(const bf16x8*)(As + (wm * 64 + mi * 16 + col16) * 32 + kslot * 8);
#pragma unroll
        for (int ni = 0; ni < 4; ++ni)
            bfr[ni] = *(const bf16x8*)(Bs + (wn * 64 + ni * 16 + col16) * 32 + kslot * 8);
#pragma unroll
        for (int mi = 0; mi < 4; ++mi)
#pragma unroll
            for (int ni = 0; ni < 4; ++ni)
                acc[mi][ni] = __builtin_amdgcn_mfma_f32_16x16x32_bf16(af[mi], bfr[ni], acc[mi][ni], 0, 0, 0);
        __syncthreads();
    }
    // ---- epilogue: stage C in LDS (XOR-swizzled 16B chunks), coalesced store
#pragma unroll
    for (int mi = 0; mi < 4; ++mi)
#pragma unroll
        for (int ni = 0; ni < 4; ++ni) {
            const int c = wn * 64 + ni * 16 + col16;
#pragma unroll
            for (int q = 0; q < 4; ++q) {
                const int r = wm * 64 + mi * 16 + kslot * 4 + q;
                const uint32_t boff = (uint32_t)((r * 256 + c * 2) ^ ((r & 7) << 4));
                *(u16*)((char*)smem + boff) = f2bf(acc[mi][ni][q]);
            }
        }
    __syncthreads();
    const size_t nbase = (size_t)(dircol * 128 + hblk0) * 32;
#pragma unroll
    for (int it = 0; it < 8; ++it) {
        const int o = tid + it * 256;               // 16B-chunk id, 0..2047
        const int r = o >> 4;
        const uint32_t soff = (uint32_t)((o * 16) ^ ((r & 7) << 4));
        bf16x8 v = *(const bf16x8*)((const char*)smem + soff);
        *(bf16x8*)(Cp + (size_t)(bm * 128 + r) * 8192 + nbase + (o & 15) * 8) = v;
    }
}

// ---------------- persistent recurrent kernel (R7 structure, best measured) ----
// 256 wgs x 512 thr, 1 wg/CU. wg -> (dir = wg>>7, hblk = wg&127): 32 gate-cols.
// Waves: (mtile 0..3, khalf 0..1). h layout: [step][dir][src_wg][row][8] —
// each wg's slice is ONE contiguous 1 KB block, written by wave0 as a single
// global_store_dwordx4 fan (64 lanes x 16B), acked once, then a padded flag.
// khalf-k waves consume ONLY producers [k*64, k*64+64) -> each wave polls its
// own 64 flags (one dword/lane, 128B-strided) and proceeds independently.
// Rotating addresses -> cached h loads safe with zero cache maintenance.
__global__ __launch_bounds__(512, 1) void k_lstm(
    const u16* __restrict__ xp, const u16* __restrict__ whp,
    const float* __restrict__ bsum, u16* hrot,
    float* __restrict__ obuf, unsigned* cnt) {
    __shared__ __align__(16) u16 wlds[32768];    // 64 KB Wh slice
    __shared__ float glds[2][64][35];            // [khalf][row][col] partial gates
    __shared__ __align__(16) u16 hxch[64][8];    // h exchange (contiguous rows)
    const int wg = blockIdx.x;
    const int dir = wg >> 7, hblk = wg & 127;
    const int tid = threadIdx.x;
    const int wid = tid >> 6, lane = tid & 63;
    const int mtile = wid & 3, khalf = wid >> 2;
    const int col16 = lane & 15, kslot = lane >> 4;
    {   // preload Wh slice (swizzle baked in by k_packwh)
        const u32x4* s = (const u32x4*)(whp + (size_t)wg * 32768);
        u32x4* d = (u32x4*)wlds;
#pragma unroll
        for (int i = 0; i < 8; ++i) d[tid + i * 512] = s[tid + i * 512];
    }
    const int fb = tid >> 3, fh = tid & 7;       // finish-phase (batch, h-sub)
    const int hidx = hblk * 8 + fh;
    const int arow = mtile * 16 + col16;         // batch row for A-frags
    float bsF[4];
#pragma unroll
    for (int g = 0; g < 4; ++g) bsF[g] = bsum[dir * 4096 + g * 1024 + hidx];
    // per-wave poll pointer: this wave's 64 producers, flags padded 128 B apart
    const unsigned* pollp = cnt + (size_t)(dir * 128 + khalf * 64 + lane) * 32;
    unsigned* flag_own = cnt + (size_t)(dir * 128 + hblk) * 32;
    float cc = 0.f;
    ushort4 xv;
    xv = *(const ushort4*)(xp + ((size_t)((dir ? (T_ - 1) : 0) * 64 + fb) * 256 + wg) * 32 + fh * 4);
    __syncthreads();                              // wlds ready
    for (int s = 0; s < T_; ++s) {
        if (s > 0) {                              // EVERY wave polls its own 64 flags
            const unsigned target = (unsigned)s;
            for (;;) {
                unsigned f;
                ldg4_cc(f, pollp);
                wait_vm0();
                if (__all(f >= target)) break;
                __builtin_amdgcn_s_sleep(1);
            }
        }
        __builtin_amdgcn_sched_barrier(0);        // pin h loads behind the poll
        // ---- h @ Wh^T : cached 16B A-frag loads from contiguous per-wg slices
        const u16* hbase = hrot + (size_t)(s * 2 + dir) * 131072
                         + (size_t)(khalf * 64) * 512 + arow * 8;
        bf16x8 hf[16];
#pragma unroll
        for (int kk = 0; kk < 16; ++kk)
            hf[kk] = *(const bf16x8*)(hbase + (size_t)(kk * 4 + kslot) * 512);
        f32x4 acc0 = {0.f, 0.f, 0.f, 0.f}, acc1 = {0.f, 0.f, 0.f, 0.f};
#pragma unroll
        for (int kk = 0; kk < 16; ++kk) {
            const int kc = khalf * 64 + kk * 4 + kslot;
            const uint32_t base = (uint32_t)(kc * 512);
            const uint32_t sw = (uint32_t)((kc & 3) << 4);
            bf16x8 b0 = *(const bf16x8*)((const char*)wlds + ((base + (uint32_t)(col16 * 16)) ^ sw));
            bf16x8 b1 = *(const bf16x8*)((const char*)wlds + ((base + (uint32_t)(256 + col16 * 16)) ^ sw));
            acc0 = __builtin_amdgcn_mfma_f32_16x16x32_bf16(hf[kk], b0, acc0, 0, 0, 0);
            acc1 = __builtin_amdgcn_mfma_f32_16x16x32_bf16(hf[kk], b1, acc1, 0, 0, 0);
        }
#pragma unroll
        for (int q = 0; q < 4; ++q) {
            glds[khalf][mtile * 16 + kslot * 4 + q][col16]      = acc0[q];
            glds[khalf][mtile * 16 + kslot * 4 + q][16 + col16] = acc1[q];
        }
        __syncthreads();                          // sync A: gates ready
        // ---- finish: gates -> elementwise -> h into LDS exchange ----
        const float gi = glds[0][fb][fh]      + glds[1][fb][fh]      + bsF[0] + bf2f(xv.x);
        const float gf = glds[0][fb][8 + fh]  + glds[1][fb][8 + fh]  + bsF[1] + bf2f(xv.y);
        const float gc = glds[0][fb][16 + fh] + glds[1][fb][16 + fh] + bsF[2] + bf2f(xv.z);
        const float go = glds[0][fb][24 + fh] + glds[1][fb][24 + fh] + bsF[3] + bf2f(xv.w);
        const float iv = sigm(gi), fv = sigm(gf), gv = tanh_f(gc), ov = sigm(go);
        cc = fv * cc + iv * gv;
        const float hv = ov * tanh_f(cc);
        hxch[fb][fh] = f2bf(hv);
        if (s == T_ - 1) obuf[(size_t)(dir * 64 + fb) * 1024 + hidx] = ov;
        __syncthreads();                          // sync B: hxch ready
        if (wid == 0) {                           // wave0: 1-instr publish + flag
            bf16x8 hv8 = *(const bf16x8*)(&hxch[lane][0]);
            u16* hst = hrot + (size_t)((s + 1) * 2 + dir) * 131072
                     + (size_t)hblk * 512 + lane * 8;
            stg16_cc(hst, hv8);
            wait_vm0();                           // single-instruction ack
            if (lane == 0) stg4_cc(flag_own, (unsigned)(s + 1));
        }
        if (s < T_ - 1) {                         // xp prefetch for step s+1
            const int tn = dir ? (T_ - 2 - s) : (s + 1);
            xv = *(const ushort4*)(xp + ((size_t)(tn * 64 + fb) * 256 + wg) * 32 + fh * 4);
        }
    }
}

// ---------------- epilogue ----------------

__global__ void k_osum(const float* __restrict__ obuf, u16* __restrict__ osum) {
    const int i = blockIdx.x * 256 + threadIdx.x;   // 65536
    osum[i] = f2bf(obuf[i] + obuf[65536 + i]);
}

__global__ __launch_bounds__(256) void k_cls(const u16* __restrict__ osum,
                                             const float* __restrict__ W,
                                             const float* __restrict__ bias,
                                             float* __restrict__ out) {
    const int blk = blockIdx.x;                     // 0..249
    const int tid = threadIdx.x, wid = tid >> 6, lane = tid & 63;
    const int col16 = lane & 15, kslot = lane >> 4;
    const int ncol0 = blk * 128 + wid * 32;
    f32x4 acc[4][2] = {};
    for (int kk = 0; kk < 32; ++kk) {
        const int kof = kk * 32 + kslot * 8;
        bf16x8 a[4];
#pragma unroll
        for (int mi = 0; mi < 4; ++mi)
            a[mi] = *(const bf16x8*)(osum + (mi * 16 + col16) * 1024 + kof);
#pragma unroll
        for (int nt = 0; nt < 2; ++nt) {
            const float* wr = W + (size_t)(ncol0 + nt * 16 + col16) * 1024 + kof;
            float4 w0 = *(const float4*)wr;
            float4 w1 = *(const float4*)(wr + 4);
            union { bf16x8 v; u16 u[8]; } bb;
            bb.u[0] = f2bf(w0.x); bb.u[1] = f2bf(w0.y); bb.u[2] = f2bf(w0.z); bb.u[3] = f2bf(w0.w);
            bb.u[4] = f2bf(w1.x); bb.u[5] = f2bf(w1.y); bb.u[6] = f2bf(w1.z); bb.u[7] = f2bf(w1.w);
#pragma unroll
            for (int mi = 0; mi < 4; ++mi)
                acc[mi][nt] = __builtin_amdgcn_mfma_f32_16x16x32_bf16(a[mi], bb.v, acc[mi][nt], 0, 0, 0);
        }
    }
#pragma unroll
    for (int nt = 0; nt < 2; ++nt) {
        const int cn = ncol0 + nt * 16 + col16;
        const float bv = bias[cn];
#pragma unroll
        for (int mi = 0; mi < 4; ++mi)
#pragma unroll
            for (int q = 0; q < 4; ++q)
                out[(size_t)(mi * 16 + kslot * 4 + q) * CLS + cn] = acc[mi][nt][q] + bv;
    }
}

// ---------------- launcher ----------------

extern "C" void kernel_launch(void* const* d_in, const int* in_sizes, int n_in,
                              void* d_out, int out_size, void* d_ws, size_t ws_size,
                              hipStream_t stream) {
    const int*   X   = (const int*)d_in[0];
    const float* emb = (const float*)d_in[1];
    const float* Wi1 = (const float*)d_in[2];
    const float* Wh1 = (const float*)d_in[3];
    const float* bi1 = (const float*)d_in[4];
    const float* bh1 = (const float*)d_in[5];
    const float* Wi2 = (const float*)d_in[6];
    const float* Wh2 = (const float*)d_in[7];
    const float* bi2 = (const float*)d_in[8];
    const float* bh2 = (const float*)d_in[9];
    const float* W   = (const float*)d_in[10];
    const float* bb  = (const float*)d_in[11];
    float* out = (float*)d_out;
    char* ws = (char*)d_ws;

    u16*      xbf   = (u16*)(ws + OFF_XBF);
    u16*      wiall = (u16*)(ws + OFF_WIALL);
    u16*      xpb   = (u16*)(ws + OFF_XP);
    u16*      whp   = (u16*)(ws + OFF_WHP);
    float*    bsum  = (float*)(ws + OFF_BSUM);
    float*    obuf  = (float*)(ws + OFF_OBUF);
    u16*      osum  = (u16*)(ws + OFF_OSUM);
    u16*      hrot  = (u16*)(ws + OFF_HROT);
    unsigned* cnt   = (unsigned*)(ws + OFF_CNT);   // aliases xbf (dead after GEMM)

    k_gather<<<dim3(16384), dim3(256), 0, stream>>>(X, emb, xbf);
    k_cvt<<<dim3(4096), dim3(256), 0, stream>>>(Wi1, wiall);
    k_cvt<<<dim3(4096), dim3(256), 0, stream>>>(Wi2, wiall + 4194304);
    k_packwh<<<dim3(4096), dim3(256), 0, stream>>>(Wh1, Wh2, whp);
    k_bias<<<dim3(32), dim3(256), 0, stream>>>(bi1, bh1, bi2, bh2, bsum);
    hipMemsetAsync(hrot, 0, 524288, stream);       // h_0 = 0 for BOTH dirs
    k_gemm_xp<<<dim3(8192), dim3(256), 0, stream>>>(xbf, wiall, xpb);
    hipMemsetAsync(cnt, 0, 32768, stream);         // xbf dead; padded flags live there
    {
        const u16* xp_p = xpb; const u16* whp_p = whp; const float* bs_p = bsum;
        u16* hr_p = hrot; float* ob_p = obuf; unsigned* cnt_p = cnt;
        void* args[] = { (void*)&xp_p, (void*)&whp_p, (void*)&bs_p,
                         (void*)&hr_p, (void*)&ob_p, (void*)&cnt_p };
        hipError_t e = hipLaunchCooperativeKernel((void*)k_lstm, dim3(NWG), dim3(512),
                                                  args, 0, stream);
        if (e != hipSuccess) {
            // fallback: 256 wgs at 1 wg/CU are co-resident on a 256-CU chip
            k_lstm<<<dim3(NWG), dim3(512), 0, stream>>>(xpb, whp, bsum, hrot, obuf, cnt);
        }
    }
    k_osum<<<dim3(256), dim3(256), 0, stream>>>(obuf, osum);
    k_cls<<<dim3(250), dim3(256), 0, stream>>>(osum, W, bb, out);
    (void)in_sizes; (void)n_in; (void)out_size; (void)ws_size;
}

// Round 12
// 1752.919 us; speedup vs baseline: 1.5146x; 1.0052x over previous
//
#include <hip/hip_runtime.h>
#include <hip/hip_bf16.h>
#include <stdint.h>

typedef __attribute__((ext_vector_type(4))) float    f32x4;
typedef __attribute__((ext_vector_type(8))) short    bf16x8;
typedef __attribute__((ext_vector_type(4))) uint32_t u32x4;
typedef unsigned short u16;

#define T_   256
#define B_   64
#define E_   1024
#define H_   1024
#define CLS  32000
#define NWG  256

// workspace layout (bytes)
#define OFF_XBF   0ull            // [16384][1024] bf16       33,554,432 (LIVE through k_lstm)
#define OFF_WHP   33554432ull     // [256 wg][Wi 64KB | Wh 64KB] 33,554,432
#define OFF_FLG   67108864ull     // [2*128] flags, 128B apart    32,768
#define OFF_BSUM  67141632ull     // [2][4096] f32                32,768
#define OFF_OBUF  67174400ull     // [2 dir][64][1024] f32       524,288
#define OFF_OSUM  67698688ull     // [64][1024] bf16             131,072
#define OFF_HROT  67829760ull     // rotating h: slot (s,dir) = (s*2+dir)*131072 B; 67,371,008

__device__ __forceinline__ u16 f2bf(float f) {
    union { float f; uint32_t i; } v; v.f = f;
    uint32_t r = v.i + 0x7fffu + ((v.i >> 16) & 1u);
    return (u16)(r >> 16);
}
__device__ __forceinline__ float sigm(float x)   { return 1.f / (1.f + __expf(-x)); }
__device__ __forceinline__ float tanh_f(float x) { return 1.f - 2.f / (__expf(2.f * x) + 1.f); }

// agent-coherent (MALL) accesses — bypass L1/L2, no cache-wide ops anywhere
__device__ __forceinline__ void ldg4_cc(unsigned& d, const unsigned* p) {
    asm volatile("global_load_dword %0, %1, off sc0 sc1"
                 : "=v"(d) : "v"(p) : "memory");
}
__device__ __forceinline__ void stg16_cc(u16* p, bf16x8 v) {
    asm volatile("global_store_dwordx4 %0, %1, off sc0 sc1"
                 :: "v"(p), "v"(v) : "memory");
}
__device__ __forceinline__ void stg4_cc(unsigned* p, unsigned v) {
    asm volatile("global_store_dword %0, %1, off sc0 sc1"
                 :: "v"(p), "v"(v) : "memory");
}
__device__ __forceinline__ void wait_vm0() {
    asm volatile("s_waitcnt vmcnt(0)" ::: "memory");
}

// ---------------- prep kernels ----------------

__global__ void k_gather(const int* __restrict__ X, const float* __restrict__ emb,
                         u16* __restrict__ xbf) {
    const int m = blockIdx.x;            // t*64+b
    const int t = m >> 6, b = m & 63;
    const int tok = X[b * T_ + t];
    const float* src = emb + (size_t)tok * E_;
    u16* dst = xbf + (size_t)m * E_;
    const int e = threadIdx.x * 4;
    float4 v = *(const float4*)(src + e);
    ushort4 o; o.x = f2bf(v.x); o.y = f2bf(v.y); o.z = f2bf(v.z); o.w = f2bf(v.w);
    *(ushort4*)(dst + e) = o;
}

// pack [Wi | Wh] per logical wg, B-fragment order, XOR-swizzled 16B groups.
// half 0 = Wi (first 64KB of wg slice), half 1 = Wh (second 64KB).
__global__ void k_packw(const float* __restrict__ Wi1, const float* __restrict__ Wh1,
                        const float* __restrict__ Wi2, const float* __restrict__ Wh2,
                        u16* __restrict__ whp) {
    const int gi  = blockIdx.x * 256 + threadIdx.x;    // 0..2,097,151
    const int half = gi >> 20;
    const int r   = gi & 1048575;
    const int wg  = r >> 12;
    const int lin = r & 4095;
    const int kc  = lin & 127;
    const int col = lin >> 7;                          // 0..31
    const int dir = wg >> 7, hblk = wg & 127;
    const int g = col >> 3, hh = col & 7;
    const float* W = half ? (dir ? Wh2 : Wh1) : (dir ? Wi2 : Wi1);
    const float* src = W + (size_t)(g * H_ + hblk * 8 + hh) * H_ + kc * 8;
    float4 v0 = *(const float4*)(src);
    float4 v1 = *(const float4*)(src + 4);
    const uint32_t boff = (uint32_t)(((kc * 32 + col) * 16) ^ ((kc & 3) << 4));
    u16* dst = whp + (size_t)wg * 65536 + half * 32768 + boff / 2;
    ushort4 o0, o1;
    o0.x = f2bf(v0.x); o0.y = f2bf(v0.y); o0.z = f2bf(v0.z); o0.w = f2bf(v0.w);
    o1.x = f2bf(v1.x); o1.y = f2bf(v1.y); o1.z = f2bf(v1.z); o1.w = f2bf(v1.w);
    *(ushort4*)dst = o0;
    *(ushort4*)(dst + 4) = o1;
}

__global__ void k_bias(const float* __restrict__ bi1, const float* __restrict__ bh1,
                       const float* __restrict__ bi2, const float* __restrict__ bh2,
                       float* __restrict__ bsum) {
    const int i = blockIdx.x * 256 + threadIdx.x;     // 0..8191
    bsum[i] = (i < 4096) ? (bi1[i] + bh1[i]) : (bi2[i - 4096] + bh2[i - 4096]);
}

// ---------------- fused persistent recurrent kernel ----------------
// 256 wgs x 512 thr, 1 wg/CU. wg -> (dir = wg>>7, hblk = wg&127): 32 gate-cols.
// Waves: (mtile 0..3, khalf 0..1). Sync/publish structure = R7 (best measured,
// frozen): per-wg contiguous 1KB h slice, wave0 single-dwordx4 publish + ack +
// padded flag; every wave polls its khalf's 64 producer flags independently.
// NEW: the input projection xp = x_t @ Wi_wg is computed JUST-IN-TIME each step
// (zero cross-wg deps) and accumulated into the same fp32 acc as h @ Wh —
// gates = [x_t | h] @ [Wi|Wh]^T, K=2048. x A-frags issue BEFORE the poll
// (latency hidden under the flag wait); xbf is LLC-resident and L2-shared by
// the 32 wgs of each XCD. This deletes the standalone 300us xp GEMM + its
// 268MB buffer + 537MB/dispatch HBM streaming.
__global__ __launch_bounds__(512, 1) void k_lstm(
    const u16* __restrict__ xbf, const u16* __restrict__ whp,
    const float* __restrict__ bsum, u16* hrot,
    float* __restrict__ obuf, unsigned* cnt) {
    __shared__ __align__(16) u16 wlds[65536];    // 128 KB: [Wi | Wh] slice
    __shared__ float glds[2][64][35];            // [khalf][row][col] partial gates
    __shared__ __align__(16) u16 hxch[64][8];    // h exchange (contiguous rows)
    const int wg = blockIdx.x;
    const int dir = wg >> 7, hblk = wg & 127;
    const int tid = threadIdx.x;
    const int wid = tid >> 6, lane = tid & 63;
    const int mtile = wid & 3, khalf = wid >> 2;
    const int col16 = lane & 15, kslot = lane >> 4;
    {   // preload [Wi|Wh] slice (swizzle baked in by k_packw): 128 KB
        const u32x4* s = (const u32x4*)(whp + (size_t)wg * 65536);
        u32x4* d = (u32x4*)wlds;
#pragma unroll
        for (int i = 0; i < 16; ++i) d[tid + i * 512] = s[tid + i * 512];
    }
    const int fb = tid >> 3, fh = tid & 7;       // finish-phase (batch, h-sub)
    const int hidx = hblk * 8 + fh;
    const int arow = mtile * 16 + col16;         // batch row for A-frags
    float bsF[4];
#pragma unroll
    for (int g = 0; g < 4; ++g) bsF[g] = bsum[dir * 4096 + g * 1024 + hidx];
    // per-wave poll pointer: this wave's 64 producers, flags padded 128 B apart
    const unsigned* pollp = cnt + (size_t)(dir * 128 + khalf * 64 + lane) * 32;
    unsigned* flag_own = cnt + (size_t)(dir * 128 + hblk) * 32;
    float cc = 0.f;
    __syncthreads();                              // wlds ready
    for (int s = 0; s < T_; ++s) {
        const int t = dir ? (T_ - 1 - s) : s;
        // ---- x-part A-frags: issue BEFORE the poll (no sync dependency) ----
        const u16* xrow = xbf + (size_t)(t * 64 + arow) * 1024 + khalf * 512;
        bf16x8 xa[16];
#pragma unroll
        for (int kk = 0; kk < 16; ++kk)
            xa[kk] = *(const bf16x8*)(xrow + kk * 32 + kslot * 8);
        if (s > 0) {                              // EVERY wave polls its own 64 flags
            const unsigned target = (unsigned)s;
            for (;;) {
                unsigned f;
                ldg4_cc(f, pollp);
                wait_vm0();
                if (__all(f >= target)) break;
                __builtin_amdgcn_s_sleep(1);
            }
        }
        __builtin_amdgcn_sched_barrier(0);        // pin h loads behind the poll
        // ---- h A-frags (issue; in flight during x-part MFMA) ----
        const u16* hbase = hrot + (size_t)(s * 2 + dir) * 131072
                         + (size_t)(khalf * 64) * 512 + arow * 8;
        bf16x8 hf[16];
#pragma unroll
        for (int kk = 0; kk < 16; ++kk)
            hf[kk] = *(const bf16x8*)(hbase + (size_t)(kk * 4 + kslot) * 512);
        f32x4 acc0 = {0.f, 0.f, 0.f, 0.f}, acc1 = {0.f, 0.f, 0.f, 0.f};
        // ---- x-part: acc += xa @ Wi (first 64KB of wlds) ----
#pragma unroll
        for (int kk = 0; kk < 16; ++kk) {
            const int kc = khalf * 64 + kk * 4 + kslot;
            const uint32_t base = (uint32_t)(kc * 512);
            const uint32_t sw = (uint32_t)((kc & 3) << 4);
            bf16x8 b0 = *(const bf16x8*)((const char*)wlds + ((base + (uint32_t)(col16 * 16)) ^ sw));
            bf16x8 b1 = *(const bf16x8*)((const char*)wlds + ((base + (uint32_t)(256 + col16 * 16)) ^ sw));
            acc0 = __builtin_amdgcn_mfma_f32_16x16x32_bf16(xa[kk], b0, acc0, 0, 0, 0);
            acc1 = __builtin_amdgcn_mfma_f32_16x16x32_bf16(xa[kk], b1, acc1, 0, 0, 0);
        }
        // ---- h-part: acc += hf @ Wh (second 64KB of wlds) ----
#pragma unroll
        for (int kk = 0; kk < 16; ++kk) {
            const int kc = khalf * 64 + kk * 4 + kslot;
            const uint32_t base = (uint32_t)(65536 + kc * 512);
            const uint32_t sw = (uint32_t)((kc & 3) << 4);
            bf16x8 b0 = *(const bf16x8*)((const char*)wlds + ((base + (uint32_t)(col16 * 16)) ^ sw));
            bf16x8 b1 = *(const bf16x8*)((const char*)wlds + ((base + (uint32_t)(256 + col16 * 16)) ^ sw));
            acc0 = __builtin_amdgcn_mfma_f32_16x16x32_bf16(hf[kk], b0, acc0, 0, 0, 0);
            acc1 = __builtin_amdgcn_mfma_f32_16x16x32_bf16(hf[kk], b1, acc1, 0, 0, 0);
        }
#pragma unroll
        for (int q = 0; q < 4; ++q) {
            glds[khalf][mtile * 16 + kslot * 4 + q][col16]      = acc0[q];
            glds[khalf][mtile * 16 + kslot * 4 + q][16 + col16] = acc1[q];
        }
        __syncthreads();                          // sync A: gates ready
        // ---- finish: gates -> elementwise -> h into LDS exchange ----
        const float gi = glds[0][fb][fh]      + glds[1][fb][fh]      + bsF[0];
        const float gf = glds[0][fb][8 + fh]  + glds[1][fb][8 + fh]  + bsF[1];
        const float gc = glds[0][fb][16 + fh] + glds[1][fb][16 + fh] + bsF[2];
        const float go = glds[0][fb][24 + fh] + glds[1][fb][24 + fh] + bsF[3];
        const float iv = sigm(gi), fv = sigm(gf), gv = tanh_f(gc), ov = sigm(go);
        cc = fv * cc + iv * gv;
        const float hv = ov * tanh_f(cc);
        hxch[fb][fh] = f2bf(hv);
        if (s == T_ - 1) obuf[(size_t)(dir * 64 + fb) * 1024 + hidx] = ov;
        __syncthreads();                          // sync B: hxch ready
        if (wid == 0) {                           // wave0: 1-instr publish + flag
            bf16x8 hv8 = *(const bf16x8*)(&hxch[lane][0]);
            u16* hst = hrot + (size_t)((s + 1) * 2 + dir) * 131072
                     + (size_t)hblk * 512 + lane * 8;
            stg16_cc(hst, hv8);
            wait_vm0();                           // single-instruction ack
            if (lane == 0) stg4_cc(flag_own, (unsigned)(s + 1));
        }
    }
}

// ---------------- epilogue ----------------

__global__ void k_osum(const float* __restrict__ obuf, u16* __restrict__ osum) {
    const int i = blockIdx.x * 256 + threadIdx.x;   // 65536
    osum[i] = f2bf(obuf[i] + obuf[65536 + i]);
}

__global__ __launch_bounds__(256) void k_cls(const u16* __restrict__ osum,
                                             const float* __restrict__ W,
                                             const float* __restrict__ bias,
                                             float* __restrict__ out) {
    const int blk = blockIdx.x;                     // 0..249
    const int tid = threadIdx.x, wid = tid >> 6, lane = tid & 63;
    const int col16 = lane & 15, kslot = lane >> 4;
    const int ncol0 = blk * 128 + wid * 32;
    f32x4 acc[4][2] = {};
    for (int kk = 0; kk < 32; ++kk) {
        const int kof = kk * 32 + kslot * 8;
        bf16x8 a[4];
#pragma unroll
        for (int mi = 0; mi < 4; ++mi)
            a[mi] = *(const bf16x8*)(osum + (mi * 16 + col16) * 1024 + kof);
#pragma unroll
        for (int nt = 0; nt < 2; ++nt) {
            const float* wr = W + (size_t)(ncol0 + nt * 16 + col16) * 1024 + kof;
            float4 w0 = *(const float4*)wr;
            float4 w1 = *(const float4*)(wr + 4);
            union { bf16x8 v; u16 u[8]; } bb;
            bb.u[0] = f2bf(w0.x); bb.u[1] = f2bf(w0.y); bb.u[2] = f2bf(w0.z); bb.u[3] = f2bf(w0.w);
            bb.u[4] = f2bf(w1.x); bb.u[5] = f2bf(w1.y); bb.u[6] = f2bf(w1.z); bb.u[7] = f2bf(w1.w);
#pragma unroll
            for (int mi = 0; mi < 4; ++mi)
                acc[mi][nt] = __builtin_amdgcn_mfma_f32_16x16x32_bf16(a[mi], bb.v, acc[mi][nt], 0, 0, 0);
        }
    }
#pragma unroll
    for (int nt = 0; nt < 2; ++nt) {
        const int cn = ncol0 + nt * 16 + col16;
        const float bv = bias[cn];
#pragma unroll
        for (int mi = 0; mi < 4; ++mi)
#pragma unroll
            for (int q = 0; q < 4; ++q)
                out[(size_t)(mi * 16 + kslot * 4 + q) * CLS + cn] = acc[mi][nt][q] + bv;
    }
}

// ---------------- launcher ----------------

extern "C" void kernel_launch(void* const* d_in, const int* in_sizes, int n_in,
                              void* d_out, int out_size, void* d_ws, size_t ws_size,
                              hipStream_t stream) {
    const int*   X   = (const int*)d_in[0];
    const float* emb = (const float*)d_in[1];
    const float* Wi1 = (const float*)d_in[2];
    const float* Wh1 = (const float*)d_in[3];
    const float* bi1 = (const float*)d_in[4];
    const float* bh1 = (const float*)d_in[5];
    const float* Wi2 = (const float*)d_in[6];
    const float* Wh2 = (const float*)d_in[7];
    const float* bi2 = (const float*)d_in[8];
    const float* bh2 = (const float*)d_in[9];
    const float* W   = (const float*)d_in[10];
    const float* bb  = (const float*)d_in[11];
    float* out = (float*)d_out;
    char* ws = (char*)d_ws;

    u16*      xbf   = (u16*)(ws + OFF_XBF);
    u16*      whp   = (u16*)(ws + OFF_WHP);
    unsigned* cnt   = (unsigned*)(ws + OFF_FLG);
    float*    bsum  = (float*)(ws + OFF_BSUM);
    float*    obuf  = (float*)(ws + OFF_OBUF);
    u16*      osum  = (u16*)(ws + OFF_OSUM);
    u16*      hrot  = (u16*)(ws + OFF_HROT);

    k_gather<<<dim3(16384), dim3(256), 0, stream>>>(X, emb, xbf);
    k_packw<<<dim3(8192), dim3(256), 0, stream>>>(Wi1, Wh1, Wi2, Wh2, whp);
    k_bias<<<dim3(32), dim3(256), 0, stream>>>(bi1, bh1, bi2, bh2, bsum);
    hipMemsetAsync(hrot, 0, 262144, stream);       // h_0 = 0 for BOTH dirs
    hipMemsetAsync(cnt, 0, 32768, stream);         // step flags
    {
        const u16* xb_p = xbf; const u16* whp_p = whp; const float* bs_p = bsum;
        u16* hr_p = hrot; float* ob_p = obuf; unsigned* cnt_p = cnt;
        void* args[] = { (void*)&xb_p, (void*)&whp_p, (void*)&bs_p,
                         (void*)&hr_p, (void*)&ob_p, (void*)&cnt_p };
        hipError_t e = hipLaunchCooperativeKernel((void*)k_lstm, dim3(NWG), dim3(512),
                                                  args, 0, stream);
        if (e != hipSuccess) {
            // fallback: 256 wgs at 1 wg/CU are co-resident on a 256-CU chip
            k_lstm<<<dim3(NWG), dim3(512), 0, stream>>>(xbf, whp, bsum, hrot, obuf, cnt);
        }
    }
    k_osum<<<dim3(256), dim3(256), 0, stream>>>(obuf, osum);
    k_cls<<<dim3(250), dim3(256), 0, stream>>>(osum, W, bb, out);
    (void)in_sizes; (void)n_in; (void)out_size; (void)ws_size;
}